// Round 8
// baseline (91.880 us; speedup 1.0000x reference)
//
#include <hip/hip_runtime.h>
#include <hip/hip_bf16.h>

// B=64, N=M=1024, 3-D. Chamfer + slot-L2 loss, 3 scalars.
// d^2 on MFMA 32x32x16 bf16, split-bf16 Gram pack (validated R4-R7, absmax 0.0):
//   A(point a, c=-2a): [c_hi3, c_lo3, c_hi3, h_hi, h_lo, 1, 1, 0,0,0]
//   B(point b):        [b_hi3, b_hi3, b_lo3, 1, 1, h_hi, h_lo, 0,0,0]
// Truncation split: hi = trunc16(x), lo = trunc16(x - hi) (validated R7).
// Grid = 4 jobs x 64 batches x 2 halves = 512 blocks x 512 threads.
// Inner loop: 2 A-tiles x 2 B-tiles -> 4 MFMA share 2 ds_read_b128; min3 fusion
// (fminf(rm, fminf(u0,u1)) -> v_min3_f32, 0.5 VALU instr per d^2 element).
// Finalize fused: last block (device-scope counter) computes out[0..2] with
// agent-scope acquire loads (cross-XCD-safe per G16). Counter zeroed by a
// 4-byte hipMemsetAsync node.

#define BATCH 64
#define NPTS 1024

typedef __attribute__((ext_vector_type(8))) short s16x8;
typedef __attribute__((ext_vector_type(8))) unsigned short u16x8;
typedef __attribute__((ext_vector_type(16))) float f32x16;

__device__ inline void split_bf(float v, unsigned short& hi, unsigned short& lo) {
    unsigned int bits = __float_as_uint(v);
    hi = (unsigned short)(bits >> 16);
    float rec = __uint_as_float(bits & 0xFFFF0000u);
    lo = (unsigned short)(__float_as_uint(v - rec) >> 16);
}

__device__ inline void pack_ab(float x, float y, float z,
                               u16x8& a0, u16x8& a1, u16x8& b0, u16x8& b1) {
    float h = fmaf(z, z, fmaf(y, y, x*x));
    unsigned short xh, xl, yh, yl, zh, zl;
    split_bf(x, xh, xl); split_bf(y, yh, yl); split_bf(z, zh, zl);
    unsigned short cxh, cxl, cyh, cyl, czh, czl;
    split_bf(-2.f*x, cxh, cxl); split_bf(-2.f*y, cyh, cyl); split_bf(-2.f*z, czh, czl);
    unsigned short hh, hl;
    split_bf(h, hh, hl);
    const unsigned short one = 0x3F80;
    a0 = u16x8{cxh, cyh, czh, cxl, cyl, czl, cxh, cyh};
    a1 = u16x8{czh, hh, hl, one, one, 0, 0, 0};
    b0 = u16x8{xh, yh, zh, xh, yh, zh, xl, yl};
    b1 = u16x8{zl, one, one, hh, hl, 0, 0, 0};
}

// Register-halving min-fold over the 32-col group, then sqrt + full-wave sum.
// Returns 2x (sum over the wave's 32 rows of sqrt(max(min,0))). Validated R5-R7.
__device__ inline float fold_sum(float v[16], int lane) {
    {
        const bool up = lane & 1;
        #pragma unroll
        for (int k = 0; k < 8; ++k) {
            float send = up ? v[k] : v[k+8];
            float recv = __shfl_xor(send, 1);
            v[k] = fminf(up ? v[k+8] : v[k], recv);
        }
    }
    {
        const bool up = lane & 2;
        #pragma unroll
        for (int k = 0; k < 4; ++k) {
            float send = up ? v[k] : v[k+4];
            float recv = __shfl_xor(send, 2);
            v[k] = fminf(up ? v[k+4] : v[k], recv);
        }
    }
    {
        const bool up = lane & 4;
        #pragma unroll
        for (int k = 0; k < 2; ++k) {
            float send = up ? v[k] : v[k+2];
            float recv = __shfl_xor(send, 4);
            v[k] = fminf(up ? v[k+2] : v[k], recv);
        }
    }
    {
        const bool up = lane & 8;
        float send = up ? v[0] : v[1];
        float recv = __shfl_xor(send, 8);
        v[0] = fminf(up ? v[1] : v[0], recv);
    }
    v[0] = fminf(v[0], __shfl_xor(v[0], 16));
    float d = sqrtf(fmaxf(v[0], 0.f));
    #pragma unroll
    for (int mask = 1; mask <= 32; mask <<= 1) d += __shfl_xor(d, mask);
    return d;   // each row counted twice
}

__device__ inline float aload(const float* p) {
    return __hip_atomic_load(p, __ATOMIC_ACQUIRE, __HIP_MEMORY_SCOPE_AGENT);
}

__global__ __launch_bounds__(512) void pass_kernel(
    const float* __restrict__ p1, const float* __restrict__ p2,
    const float* __restrict__ tg, const float* __restrict__ flag1,
    const float* __restrict__ flag2, const float* __restrict__ symf,
    float* __restrict__ ws, float* __restrict__ out)
{
    __shared__ __align__(16) unsigned short ybuf[16384];  // 32 KB: Y B-pack, whole batch
    __shared__ __align__(16) unsigned short abuf[8192];   // 16 KB: X A-pack, owned half
    __shared__ float red[8];
    __shared__ float redE[8];

    const int bid = blockIdx.x;
    const int j = bid >> 7, b = (bid >> 1) & 63, half = bid & 1;
    const int tid = threadIdx.x;

    const float* __restrict__ X = (j == 0) ? p1 : (j == 1) ? p2 : tg;
    const float* __restrict__ Y = (j == 2) ? p1 : (j == 3) ? p2 : tg;

    // pack Y (B-side): 2 points per thread
    #pragma unroll
    for (int ii = 0; ii < 2; ++ii) {
        const int i = tid + ii * 512;
        const size_t g = ((size_t)b * NPTS + i) * 3;
        float x = Y[g], y = Y[g+1], z = Y[g+2];
        u16x8 a0, a1, b0, b1;
        pack_ab(x, y, z, a0, a1, b0, b1);
        const int off = (i >> 5) * 512 + (i & 31) * 8;
        *(u16x8*)(ybuf + off)       = b0;
        *(u16x8*)(ybuf + off + 256) = b1;
    }
    // pack X half (A-side), 1 point per thread, + slot-L2 term (jobs 0,1)
    float e = 0.f;
    {
        const int i = half * 512 + tid;
        const size_t g = ((size_t)b * NPTS + i) * 3;
        float x = X[g], y = X[g+1], z = X[g+2];
        u16x8 a0, a1, b0, b1;
        pack_ab(x, y, z, a0, a1, b0, b1);
        const int off = (tid >> 5) * 512 + (tid & 31) * 8;
        *(u16x8*)(abuf + off)       = a0;
        *(u16x8*)(abuf + off + 256) = a1;
        if (j < 2) {
            float tx = tg[g], ty = tg[g+1], tz = tg[g+2];
            float dx = x - tx, dy = y - ty, dz = z - tz;
            e = sqrtf(fmaf(dz, dz, fmaf(dy, dy, dx*dx)));
        }
    }
    __syncthreads();

    const int lane = tid & 63, w = tid >> 6;
    const int c = lane & 31, q = lane >> 5;
    const int fo = q * 256 + c * 8;
    // wave owns row-tiles 2w and 2w+1
    const s16x8 fa0 = *(const s16x8*)(abuf + (2*w)   * 512 + fo);
    const s16x8 fa1 = *(const s16x8*)(abuf + (2*w+1) * 512 + fo);

    float rm0[16], rm1[16];
    #pragma unroll
    for (int i = 0; i < 16; ++i) { rm0[i] = 3e38f; rm1[i] = 3e38f; }
    const f32x16 zacc = {};

    const unsigned short* Yp = ybuf + fo;
    #pragma unroll 2
    for (int t = 0; t < 32; t += 2) {
        const s16x8 bb0 = *(const s16x8*)(Yp + t * 512);
        const s16x8 bb1 = *(const s16x8*)(Yp + t * 512 + 512);
        f32x16 u00 = __builtin_amdgcn_mfma_f32_32x32x16_bf16(fa0, bb0, zacc, 0, 0, 0);
        f32x16 u01 = __builtin_amdgcn_mfma_f32_32x32x16_bf16(fa0, bb1, zacc, 0, 0, 0);
        #pragma unroll
        for (int i = 0; i < 16; ++i) rm0[i] = fminf(rm0[i], fminf(u00[i], u01[i]));
        f32x16 u10 = __builtin_amdgcn_mfma_f32_32x32x16_bf16(fa1, bb0, zacc, 0, 0, 0);
        f32x16 u11 = __builtin_amdgcn_mfma_f32_32x32x16_bf16(fa1, bb1, zacc, 0, 0, 0);
        #pragma unroll
        for (int i = 0; i < 16; ++i) rm1[i] = fminf(rm1[i], fminf(u10[i], u11[i]));
    }

    // sum over the wave's 64 rows of sqrt(min d^2)
    const float s = 0.5f * (fold_sum(rm0, lane) + fold_sum(rm1, lane));
    #pragma unroll
    for (int mask = 1; mask <= 32; mask <<= 1) e += __shfl_xor(e, mask);
    if (lane == 0) { red[w] = s; redE[w] = e; }
    __syncthreads();

    // wave 0: publish partials; last block finalizes
    if (w == 0) {
        int last = 0;
        if (lane == 0) {
            float S = 0.f, E = 0.f;
            #pragma unroll
            for (int k = 0; k < 8; ++k) { S += red[k]; E += redE[k]; }
            __hip_atomic_store(&ws[bid], S, __ATOMIC_RELEASE, __HIP_MEMORY_SCOPE_AGENT);
            if (j < 2)
                __hip_atomic_store(&ws[512 + bid], E, __ATOMIC_RELEASE, __HIP_MEMORY_SCOPE_AGENT);
            unsigned prev = __hip_atomic_fetch_add((unsigned int*)&ws[1024], 1u,
                                                   __ATOMIC_ACQ_REL, __HIP_MEMORY_SCOPE_AGENT);
            last = (prev == 511u);
        }
        last = __shfl(last, 0);
        if (last) {
            const int bb = lane;   // one batch per lane
            float rowS1 = 0.f, rowS2 = 0.f, colS1 = 0.f, colS2 = 0.f, E1 = 0.f, E2 = 0.f;
            #pragma unroll
            for (int h = 0; h < 2; ++h) {
                rowS1 += aload(&ws[0*128 + bb*2 + h]);
                rowS2 += aload(&ws[1*128 + bb*2 + h]);
                colS1 += aload(&ws[2*128 + bb*2 + h]);
                colS2 += aload(&ws[3*128 + bb*2 + h]);
                E1    += aload(&ws[512 + 0*128 + bb*2 + h]);
                E2    += aload(&ws[512 + 1*128 + bb*2 + h]);
            }
            const float inv = 1.f / (float)NPTS;
            const float ch1 = 0.5f * (rowS1 + colS1) * inv;
            const float ch2 = 0.5f * (rowS2 + colS2) * inv;
            const float sf = symf[bb];
            float l1 = flag1[bb] * (sf * ch1 + (1.f - sf) * E1 * inv);
            float l2 = flag2[bb] * (sf * ch2 + (1.f - sf) * E2 * inv);
            #pragma unroll
            for (int mask = 1; mask <= 32; mask <<= 1) {
                l1 += __shfl_xor(l1, mask);
                l2 += __shfl_xor(l2, mask);
            }
            if (lane == 0) {
                const float sc = 1.f / (float)BATCH;
                out[0] = (l1 + l2) * sc;
                out[1] = l1 * sc;
                out[2] = l2 * sc;
            }
        }
    }
}

extern "C" void kernel_launch(void* const* d_in, const int* in_sizes, int n_in,
                              void* d_out, int out_size, void* d_ws, size_t ws_size,
                              hipStream_t stream) {
    const float* p1 = (const float*)d_in[0];
    const float* p2 = (const float*)d_in[1];
    const float* tg = (const float*)d_in[2];
    const float* f1 = (const float*)d_in[3];
    const float* f2 = (const float*)d_in[4];
    const float* sf = (const float*)d_in[5];
    float* out = (float*)d_out;
    float* ws = (float*)d_ws;   // [0..511] S, [512..767] E, [1024] done-counter

    hipMemsetAsync((char*)d_ws + 4096, 0, 4, stream);   // zero the done-counter
    pass_kernel<<<512, 512, 0, stream>>>(p1, p2, tg, f1, f2, sf, ws, out);
}

// Round 9
// 88.051 us; speedup vs baseline: 1.0435x; 1.0435x over previous
//
#include <hip/hip_runtime.h>
#include <hip/hip_bf16.h>

// B=64, N=M=1024, 3-D. Chamfer + slot-L2 loss, 3 scalars.
// d^2 on MFMA 32x32x16 bf16, split-bf16 Gram pack (validated R4-R8, absmax 0.0):
//   A(point a, c=-2a): [c_hi3, c_lo3, c_hi3, h_hi, h_lo, 1, 1, 0,0,0]
//   B(point b):        [b_hi3, b_hi3, b_lo3, 1, 1, h_hi, h_lo, 0,0,0]
// Truncation split: hi = trunc16(x), lo = trunc16(x - hi) (validated R7).
// Grid = 4 jobs x 64 batches x 2 halves = 512 blocks x 512 threads = 1 full round
// at 2 blocks/CU. Each wave owns TWO row-tiles SEQUENTIALLY (rm not live across
// tiles -> ~80 live VGPR, no spill; R8's unroll-2 spill was the regression).
// Inner iter: 1 A-frag x 2 B-tiles -> min3 fusion, 0.5 VALU/d^2.
// Last block (agent-scope counter) finalizes out[0..2] (G16-safe acquire loads).

#define BATCH 64
#define NPTS 1024

typedef __attribute__((ext_vector_type(8))) short s16x8;
typedef __attribute__((ext_vector_type(8))) unsigned short u16x8;
typedef __attribute__((ext_vector_type(16))) float f32x16;

__device__ inline void split_bf(float v, unsigned short& hi, unsigned short& lo) {
    unsigned int bits = __float_as_uint(v);
    hi = (unsigned short)(bits >> 16);
    float rec = __uint_as_float(bits & 0xFFFF0000u);
    lo = (unsigned short)(__float_as_uint(v - rec) >> 16);
}

__device__ inline void pack_ab(float x, float y, float z,
                               u16x8& a0, u16x8& a1, u16x8& b0, u16x8& b1) {
    float h = fmaf(z, z, fmaf(y, y, x*x));
    unsigned short xh, xl, yh, yl, zh, zl;
    split_bf(x, xh, xl); split_bf(y, yh, yl); split_bf(z, zh, zl);
    unsigned short cxh, cxl, cyh, cyl, czh, czl;
    split_bf(-2.f*x, cxh, cxl); split_bf(-2.f*y, cyh, cyl); split_bf(-2.f*z, czh, czl);
    unsigned short hh, hl;
    split_bf(h, hh, hl);
    const unsigned short one = 0x3F80;
    a0 = u16x8{cxh, cyh, czh, cxl, cyl, czl, cxh, cyh};
    a1 = u16x8{czh, hh, hl, one, one, 0, 0, 0};
    b0 = u16x8{xh, yh, zh, xh, yh, zh, xl, yl};
    b1 = u16x8{zl, one, one, hh, hl, 0, 0, 0};
}

// Register-halving min-fold over the 32-col group, then sqrt + full-wave sum.
// Returns 2x (sum over the tile's 32 rows of sqrt(max(min,0))). Validated R5-R8.
__device__ inline float fold_sum(float v[16], int lane) {
    {
        const bool up = lane & 1;
        #pragma unroll
        for (int k = 0; k < 8; ++k) {
            float send = up ? v[k] : v[k+8];
            float recv = __shfl_xor(send, 1);
            v[k] = fminf(up ? v[k+8] : v[k], recv);
        }
    }
    {
        const bool up = lane & 2;
        #pragma unroll
        for (int k = 0; k < 4; ++k) {
            float send = up ? v[k] : v[k+4];
            float recv = __shfl_xor(send, 2);
            v[k] = fminf(up ? v[k+4] : v[k], recv);
        }
    }
    {
        const bool up = lane & 4;
        #pragma unroll
        for (int k = 0; k < 2; ++k) {
            float send = up ? v[k] : v[k+2];
            float recv = __shfl_xor(send, 4);
            v[k] = fminf(up ? v[k+2] : v[k], recv);
        }
    }
    {
        const bool up = lane & 8;
        float send = up ? v[0] : v[1];
        float recv = __shfl_xor(send, 8);
        v[0] = fminf(up ? v[1] : v[0], recv);
    }
    v[0] = fminf(v[0], __shfl_xor(v[0], 16));
    float d = sqrtf(fmaxf(v[0], 0.f));
    #pragma unroll
    for (int mask = 1; mask <= 32; mask <<= 1) d += __shfl_xor(d, mask);
    return d;   // each row counted twice
}

__device__ inline float aload(const float* p) {
    return __hip_atomic_load(p, __ATOMIC_ACQUIRE, __HIP_MEMORY_SCOPE_AGENT);
}

__global__ __launch_bounds__(512, 4) void pass_kernel(
    const float* __restrict__ p1, const float* __restrict__ p2,
    const float* __restrict__ tg, const float* __restrict__ flag1,
    const float* __restrict__ flag2, const float* __restrict__ symf,
    float* __restrict__ ws, float* __restrict__ out)
{
    __shared__ __align__(16) unsigned short ybuf[16384];  // 32 KB: Y B-pack, whole batch
    __shared__ __align__(16) unsigned short abuf[8192];   // 16 KB: X A-pack, owned half (16 tiles)
    __shared__ float red[8];
    __shared__ float redE[8];

    const int bid = blockIdx.x;
    const int j = bid >> 7, b = (bid >> 1) & 63, half = bid & 1;
    const int tid = threadIdx.x;

    const float* __restrict__ X = (j == 0) ? p1 : (j == 1) ? p2 : tg;
    const float* __restrict__ Y = (j == 2) ? p1 : (j == 3) ? p2 : tg;

    // pack Y (B-side): 2 points per thread
    #pragma unroll
    for (int ii = 0; ii < 2; ++ii) {
        const int i = tid + ii * 512;
        const size_t g = ((size_t)b * NPTS + i) * 3;
        float x = Y[g], y = Y[g+1], z = Y[g+2];
        u16x8 a0, a1, b0, b1;
        pack_ab(x, y, z, a0, a1, b0, b1);
        const int off = (i >> 5) * 512 + (i & 31) * 8;
        *(u16x8*)(ybuf + off)       = b0;
        *(u16x8*)(ybuf + off + 256) = b1;
    }
    // pack X half (A-side), 1 pt/thread -> 16 tiles, + slot-L2 term (jobs 0,1)
    float e = 0.f;
    {
        const int i = half * 512 + tid;
        const size_t g = ((size_t)b * NPTS + i) * 3;
        float x = X[g], y = X[g+1], z = X[g+2];
        u16x8 a0, a1, b0, b1;
        pack_ab(x, y, z, a0, a1, b0, b1);
        const int off = (tid >> 5) * 512 + (tid & 31) * 8;
        *(u16x8*)(abuf + off)       = a0;
        *(u16x8*)(abuf + off + 256) = a1;
        if (j < 2) {
            float tx = tg[g], ty = tg[g+1], tz = tg[g+2];
            float dx = x - tx, dy = y - ty, dz = z - tz;
            e = sqrtf(fmaf(dz, dz, fmaf(dy, dy, dx*dx)));
        }
    }
    __syncthreads();

    const int lane = tid & 63, w = tid >> 6;
    const int c = lane & 31, q = lane >> 5;
    const int fo = q * 256 + c * 8;
    const unsigned short* Yp = ybuf + fo;
    const f32x16 zacc = {};

    // wave owns row-tiles 2w and 2w+1, processed SEQUENTIALLY (low live-reg set)
    float s = 0.f;
    #pragma unroll 1
    for (int sub = 0; sub < 2; ++sub) {
        const s16x8 fa = *(const s16x8*)(abuf + (2*w + sub) * 512 + fo);
        float rm[16];
        #pragma unroll
        for (int i = 0; i < 16; ++i) rm[i] = 3e38f;
        #pragma unroll 1
        for (int t = 0; t < 32; t += 2) {
            const s16x8 bb0 = *(const s16x8*)(Yp + t * 512);
            const s16x8 bb1 = *(const s16x8*)(Yp + t * 512 + 512);
            f32x16 u0 = __builtin_amdgcn_mfma_f32_32x32x16_bf16(fa, bb0, zacc, 0, 0, 0);
            f32x16 u1 = __builtin_amdgcn_mfma_f32_32x32x16_bf16(fa, bb1, zacc, 0, 0, 0);
            #pragma unroll
            for (int i = 0; i < 16; ++i) rm[i] = fminf(rm[i], fminf(u0[i], u1[i]));
        }
        s += fold_sum(rm, lane);
    }
    s *= 0.5f;   // fold_sum double-counts rows

    #pragma unroll
    for (int mask = 1; mask <= 32; mask <<= 1) e += __shfl_xor(e, mask);
    if (lane == 0) { red[w] = s; redE[w] = e; }
    __syncthreads();

    // wave 0: publish partials; last block finalizes
    if (w == 0) {
        int last = 0;
        if (lane == 0) {
            float S = 0.f, E = 0.f;
            #pragma unroll
            for (int k = 0; k < 8; ++k) { S += red[k]; E += redE[k]; }
            __hip_atomic_store(&ws[bid], S, __ATOMIC_RELEASE, __HIP_MEMORY_SCOPE_AGENT);
            if (j < 2)
                __hip_atomic_store(&ws[512 + bid], E, __ATOMIC_RELEASE, __HIP_MEMORY_SCOPE_AGENT);
            unsigned prev = __hip_atomic_fetch_add((unsigned int*)&ws[1024], 1u,
                                                   __ATOMIC_ACQ_REL, __HIP_MEMORY_SCOPE_AGENT);
            last = (prev == 511u);
        }
        last = __shfl(last, 0);
        if (last) {
            const int bb = lane;   // one batch per lane
            float rowS1 = 0.f, rowS2 = 0.f, colS1 = 0.f, colS2 = 0.f, E1 = 0.f, E2 = 0.f;
            #pragma unroll
            for (int h = 0; h < 2; ++h) {
                rowS1 += aload(&ws[0*128 + bb*2 + h]);
                rowS2 += aload(&ws[1*128 + bb*2 + h]);
                colS1 += aload(&ws[2*128 + bb*2 + h]);
                colS2 += aload(&ws[3*128 + bb*2 + h]);
                E1    += aload(&ws[512 + 0*128 + bb*2 + h]);
                E2    += aload(&ws[512 + 1*128 + bb*2 + h]);
            }
            const float inv = 1.f / (float)NPTS;
            const float ch1 = 0.5f * (rowS1 + colS1) * inv;
            const float ch2 = 0.5f * (rowS2 + colS2) * inv;
            const float sf = symf[bb];
            float l1 = flag1[bb] * (sf * ch1 + (1.f - sf) * E1 * inv);
            float l2 = flag2[bb] * (sf * ch2 + (1.f - sf) * E2 * inv);
            #pragma unroll
            for (int mask = 1; mask <= 32; mask <<= 1) {
                l1 += __shfl_xor(l1, mask);
                l2 += __shfl_xor(l2, mask);
            }
            if (lane == 0) {
                const float sc = 1.f / (float)BATCH;
                out[0] = (l1 + l2) * sc;
                out[1] = l1 * sc;
                out[2] = l2 * sc;
            }
        }
    }
}

extern "C" void kernel_launch(void* const* d_in, const int* in_sizes, int n_in,
                              void* d_out, int out_size, void* d_ws, size_t ws_size,
                              hipStream_t stream) {
    const float* p1 = (const float*)d_in[0];
    const float* p2 = (const float*)d_in[1];
    const float* tg = (const float*)d_in[2];
    const float* f1 = (const float*)d_in[3];
    const float* f2 = (const float*)d_in[4];
    const float* sf = (const float*)d_in[5];
    float* out = (float*)d_out;
    float* ws = (float*)d_ws;   // [0..511] S, [512..767] E, [1024] done-counter

    hipMemsetAsync((char*)d_ws + 4096, 0, 4, stream);   // zero the done-counter
    pass_kernel<<<512, 512, 0, stream>>>(p1, p2, tg, f1, f2, sf, ws, out);
}

// Round 10
// 73.139 us; speedup vs baseline: 1.2562x; 1.2039x over previous
//
#include <hip/hip_runtime.h>
#include <hip/hip_bf16.h>

// B=64, N=M=1024, 3-D. Chamfer + slot-L2 loss, 3 scalars.
// d^2 on MFMA 32x32x16 bf16, split-bf16 Gram pack (validated R4-R9, absmax 0.0):
//   A(point a, c=-2a): [c_hi3, c_lo3, c_hi3, h_hi, h_lo, 1, 1, 0,0,0]
//   B(point b):        [b_hi3, b_hi3, b_lo3, 1, 1, h_hi, h_lo, 0,0,0]
// Truncation split: hi = trunc16(x), lo = trunc16(x - hi) (validated R7).
// Grid = 4 jobs x 64 batches = 256 blocks x 1024 threads = 1 block/CU, 1 round.
// Each wave owns row-tiles 2w,2w+1: 2 A-frags in reg, 1 B-read feeds 2 MFMAs
// (0.5 ds_read/MFMA - the R7 shape that measured best; R9's 1.0 was the loss).
// Separate tiny finalize kernel (R8/R9 fused-finalize cost ~14us - reverted).

#define BATCH 64
#define NPTS 1024

typedef __attribute__((ext_vector_type(8))) short s16x8;
typedef __attribute__((ext_vector_type(8))) unsigned short u16x8;
typedef __attribute__((ext_vector_type(16))) float f32x16;

__device__ inline void split_bf(float v, unsigned short& hi, unsigned short& lo) {
    unsigned int bits = __float_as_uint(v);
    hi = (unsigned short)(bits >> 16);
    float rec = __uint_as_float(bits & 0xFFFF0000u);
    lo = (unsigned short)(__float_as_uint(v - rec) >> 16);
}

__device__ inline void pack_ab(float x, float y, float z,
                               u16x8& a0, u16x8& a1, u16x8& b0, u16x8& b1) {
    float h = fmaf(z, z, fmaf(y, y, x*x));
    unsigned short xh, xl, yh, yl, zh, zl;
    split_bf(x, xh, xl); split_bf(y, yh, yl); split_bf(z, zh, zl);
    unsigned short cxh, cxl, cyh, cyl, czh, czl;
    split_bf(-2.f*x, cxh, cxl); split_bf(-2.f*y, cyh, cyl); split_bf(-2.f*z, czh, czl);
    unsigned short hh, hl;
    split_bf(h, hh, hl);
    const unsigned short one = 0x3F80;
    a0 = u16x8{cxh, cyh, czh, cxl, cyl, czl, cxh, cyh};
    a1 = u16x8{czh, hh, hl, one, one, 0, 0, 0};
    b0 = u16x8{xh, yh, zh, xh, yh, zh, xl, yl};
    b1 = u16x8{zl, one, one, hh, hl, 0, 0, 0};
}

// Register-halving min-fold over the 32-col group, then sqrt + full-wave sum.
// Returns 2x (sum over the tile's 32 rows of sqrt(max(min,0))). Validated R5-R9.
__device__ inline float fold_sum(float v[16], int lane) {
    {
        const bool up = lane & 1;
        #pragma unroll
        for (int k = 0; k < 8; ++k) {
            float send = up ? v[k] : v[k+8];
            float recv = __shfl_xor(send, 1);
            v[k] = fminf(up ? v[k+8] : v[k], recv);
        }
    }
    {
        const bool up = lane & 2;
        #pragma unroll
        for (int k = 0; k < 4; ++k) {
            float send = up ? v[k] : v[k+4];
            float recv = __shfl_xor(send, 2);
            v[k] = fminf(up ? v[k+4] : v[k], recv);
        }
    }
    {
        const bool up = lane & 4;
        #pragma unroll
        for (int k = 0; k < 2; ++k) {
            float send = up ? v[k] : v[k+2];
            float recv = __shfl_xor(send, 4);
            v[k] = fminf(up ? v[k+2] : v[k], recv);
        }
    }
    {
        const bool up = lane & 8;
        float send = up ? v[0] : v[1];
        float recv = __shfl_xor(send, 8);
        v[0] = fminf(up ? v[1] : v[0], recv);
    }
    v[0] = fminf(v[0], __shfl_xor(v[0], 16));
    float d = sqrtf(fmaxf(v[0], 0.f));
    #pragma unroll
    for (int mask = 1; mask <= 32; mask <<= 1) d += __shfl_xor(d, mask);
    return d;   // each row counted twice
}

__global__ __launch_bounds__(1024, 4) void pass_kernel(
    const float* __restrict__ p1, const float* __restrict__ p2,
    const float* __restrict__ tg, float* __restrict__ ws)
{
    __shared__ __align__(16) unsigned short ybuf[16384];  // 32 KB: Y B-pack, whole batch
    __shared__ __align__(16) unsigned short abuf[16384];  // 32 KB: X A-pack, whole batch
    __shared__ float red[16];
    __shared__ float redE[16];

    const int bid = blockIdx.x;
    const int j = bid >> 6, b = bid & 63;
    const int tid = threadIdx.x;

    const float* __restrict__ X = (j == 0) ? p1 : (j == 1) ? p2 : tg;
    const float* __restrict__ Y = (j == 2) ? p1 : (j == 3) ? p2 : tg;

    // pack: each thread packs 1 Y point (B-side) + 1 X point (A-side)
    const int off = (tid >> 5) * 512 + (tid & 31) * 8;
    {
        const size_t g = ((size_t)b * NPTS + tid) * 3;
        float x = Y[g], y = Y[g+1], z = Y[g+2];
        u16x8 a0, a1, b0, b1;
        pack_ab(x, y, z, a0, a1, b0, b1);
        *(u16x8*)(ybuf + off)       = b0;
        *(u16x8*)(ybuf + off + 256) = b1;
    }
    float e = 0.f;
    {
        const size_t g = ((size_t)b * NPTS + tid) * 3;
        float x = X[g], y = X[g+1], z = X[g+2];
        u16x8 a0, a1, b0, b1;
        pack_ab(x, y, z, a0, a1, b0, b1);
        *(u16x8*)(abuf + off)       = a0;
        *(u16x8*)(abuf + off + 256) = a1;
        if (j < 2) {
            float tx = tg[g], ty = tg[g+1], tz = tg[g+2];
            float dx = x - tx, dy = y - ty, dz = z - tz;
            e = sqrtf(fmaf(dz, dz, fmaf(dy, dy, dx*dx)));
        }
    }
    __syncthreads();

    const int lane = tid & 63, w = tid >> 6;     // 16 waves
    const int c = lane & 31, q = lane >> 5;
    const int fo = q * 256 + c * 8;
    // wave owns row-tiles 2w and 2w+1 (2 A-frags live together - R7 shape)
    const s16x8 fa0 = *(const s16x8*)(abuf + (2*w)   * 512 + fo);
    const s16x8 fa1 = *(const s16x8*)(abuf + (2*w+1) * 512 + fo);

    float rm0[16], rm1[16];
    #pragma unroll
    for (int i = 0; i < 16; ++i) { rm0[i] = 3e38f; rm1[i] = 3e38f; }
    const f32x16 zacc = {};

    const unsigned short* Yp = ybuf + fo;
    #pragma unroll 2
    for (int t = 0; t < 32; ++t) {
        const s16x8 bb = *(const s16x8*)(Yp + t * 512);
        f32x16 u0 = __builtin_amdgcn_mfma_f32_32x32x16_bf16(fa0, bb, zacc, 0, 0, 0);
        f32x16 u1 = __builtin_amdgcn_mfma_f32_32x32x16_bf16(fa1, bb, zacc, 0, 0, 0);
        #pragma unroll
        for (int i = 0; i < 16; ++i) {
            rm0[i] = fminf(rm0[i], u0[i]);
            rm1[i] = fminf(rm1[i], u1[i]);
        }
    }

    // sum over the wave's 64 rows of sqrt(min d^2)
    const float s = 0.5f * (fold_sum(rm0, lane) + fold_sum(rm1, lane));
    #pragma unroll
    for (int mask = 1; mask <= 32; mask <<= 1) e += __shfl_xor(e, mask);
    if (lane == 0) { red[w] = s; redE[w] = e; }
    __syncthreads();

    if (tid == 0) {
        float S = 0.f, E = 0.f;
        #pragma unroll
        for (int k = 0; k < 16; ++k) { S += red[k]; E += redE[k]; }
        ws[bid] = S;                             // 256 S slots (j*64 + b)
        if (j < 2) ws[256 + j*64 + b] = E;       // 128 E slots
    }
}

__global__ __launch_bounds__(64) void finalize_kernel(
    const float* __restrict__ flag1, const float* __restrict__ flag2,
    const float* __restrict__ symf, const float* __restrict__ ws,
    float* __restrict__ out)
{
    const int b = threadIdx.x;   // one batch per lane
    const float rowS1 = ws[0*64 + b];
    const float rowS2 = ws[1*64 + b];
    const float colS1 = ws[2*64 + b];
    const float colS2 = ws[3*64 + b];
    const float E1    = ws[256 + b];
    const float E2    = ws[320 + b];
    const float inv = 1.f / (float)NPTS;
    const float ch1 = 0.5f * (rowS1 + colS1) * inv;
    const float ch2 = 0.5f * (rowS2 + colS2) * inv;
    const float sf = symf[b];
    float l1 = flag1[b] * (sf * ch1 + (1.f - sf) * E1 * inv);
    float l2 = flag2[b] * (sf * ch2 + (1.f - sf) * E2 * inv);
    #pragma unroll
    for (int mask = 1; mask <= 32; mask <<= 1) {
        l1 += __shfl_xor(l1, mask);
        l2 += __shfl_xor(l2, mask);
    }
    if (b == 0) {
        const float sc = 1.f / (float)BATCH;
        out[0] = (l1 + l2) * sc;
        out[1] = l1 * sc;
        out[2] = l2 * sc;
    }
}

extern "C" void kernel_launch(void* const* d_in, const int* in_sizes, int n_in,
                              void* d_out, int out_size, void* d_ws, size_t ws_size,
                              hipStream_t stream) {
    const float* p1 = (const float*)d_in[0];
    const float* p2 = (const float*)d_in[1];
    const float* tg = (const float*)d_in[2];
    const float* f1 = (const float*)d_in[3];
    const float* f2 = (const float*)d_in[4];
    const float* sf = (const float*)d_in[5];
    float* out = (float*)d_out;
    float* ws = (float*)d_ws;   // [0..255] S, [256..383] E; all read slots written

    pass_kernel<<<256, 1024, 0, stream>>>(p1, p2, tg, ws);
    finalize_kernel<<<1, 64, 0, stream>>>(f1, f2, sf, ws, out);
}